// Round 9
// baseline (20101.491 us; speedup 1.0000x reference)
//
#include <hip/hip_runtime.h>
#include <stdint.h>

// Bidirectional LSTM T=4096, B=1, I=H=1024 -> 3 classes.
// R9: R8 topology (wave-per-unit, lane=(gate,kc), PAD-68 LDS, resident
//     weights, waves_per_eu(2,2)) with three serial-chain cuts:
//     1) 2-deep PIPELINED poll (sample cadence ~issue-gap, not RTT)
//     2) raw s_barrier + lgkmcnt-only drain (compiler __syncthreads drains
//        vmcnt(0) -> was stalling on in-flight poll/prefetch loads)
//     3) unpinned xg prefetch issued post-detect, consumed next step

#define T_SEQ 4096
#define ISZ   1024
#define HID   1024
#define NB_TOT 256
#define NTHR  512
#define PAD   68

typedef unsigned long long u64;

__device__ __forceinline__ float fast_sigmoid(float x) {
    return 1.0f / (1.0f + __expf(-x));
}
__device__ __forceinline__ float fast_tanh(float x) {
    return 1.0f - 2.0f / (__expf(2.0f * x) + 1.0f);
}

#define PIN4(v) asm volatile("" : "+v"(v.x), "+v"(v.y), "+v"(v.z), "+v"(v.w))
#define DOT4(a, b) ((a).x*(b).x + (a).y*(b).y + (a).z*(b).z + (a).w*(b).w)

// ---------------- Phase 1: xg[dir][t][g] = dot(x[row(t)], Wih[g]) + bih[g] + bhh[g]
#define GM 64
#define GN 64
#define GK 32

__global__ __launch_bounds__(256)
void xproj_gemm(const float* __restrict__ x,
                const float* __restrict__ Wih_f, const float* __restrict__ bih_f,
                const float* __restrict__ bhh_f,
                const float* __restrict__ Wih_b, const float* __restrict__ bih_b,
                const float* __restrict__ bhh_b,
                float* __restrict__ xg)
{
    const int dir = blockIdx.z;
    const float* Wih = dir ? Wih_b : Wih_f;
    const float* bih = dir ? bih_b : bih_f;
    const float* bhh = dir ? bhh_b : bhh_f;
    const int m0 = blockIdx.y * GM;
    const int n0 = blockIdx.x * GN;
    const int tid = threadIdx.x;
    const int ms = tid >> 2;
    const int kq = tid & 3;
    const int tm = tid >> 4;
    const int tn = tid & 15;

    __shared__ float As[GK][GM + 4];
    __shared__ float Bs[GK][GN + 4];

    float acc[4][4] = {};

    const int mrow = m0 + ms;
    const int xrow = dir ? (T_SEQ - 1 - mrow) : mrow;
    const float* ap = x + (size_t)xrow * ISZ + kq * 8;
    const float* bp = Wih + (size_t)(n0 + ms) * ISZ + kq * 8;

    for (int k0 = 0; k0 < ISZ; k0 += GK) {
        float4 a0 = *(const float4*)(ap + k0);
        float4 a1 = *(const float4*)(ap + k0 + 4);
        float4 b0 = *(const float4*)(bp + k0);
        float4 b1 = *(const float4*)(bp + k0 + 4);
        __syncthreads();
        const int kb = kq * 8;
        As[kb+0][ms]=a0.x; As[kb+1][ms]=a0.y; As[kb+2][ms]=a0.z; As[kb+3][ms]=a0.w;
        As[kb+4][ms]=a1.x; As[kb+5][ms]=a1.y; As[kb+6][ms]=a1.z; As[kb+7][ms]=a1.w;
        Bs[kb+0][ms]=b0.x; Bs[kb+1][ms]=b0.y; Bs[kb+2][ms]=b0.z; Bs[kb+3][ms]=b0.w;
        Bs[kb+4][ms]=b1.x; Bs[kb+5][ms]=b1.y; Bs[kb+6][ms]=b1.z; Bs[kb+7][ms]=b1.w;
        __syncthreads();
        #pragma unroll
        for (int k = 0; k < GK; ++k) {
            float4 av = *(const float4*)&As[k][tm * 4];
            float4 bv = *(const float4*)&Bs[k][tn * 4];
            acc[0][0] += av.x*bv.x; acc[0][1] += av.x*bv.y; acc[0][2] += av.x*bv.z; acc[0][3] += av.x*bv.w;
            acc[1][0] += av.y*bv.x; acc[1][1] += av.y*bv.y; acc[1][2] += av.y*bv.z; acc[1][3] += av.y*bv.w;
            acc[2][0] += av.z*bv.x; acc[2][1] += av.z*bv.y; acc[2][2] += av.z*bv.z; acc[2][3] += av.z*bv.w;
            acc[3][0] += av.w*bv.x; acc[3][1] += av.w*bv.y; acc[3][2] += av.w*bv.z; acc[3][3] += av.w*bv.w;
        }
    }

    const int gc = n0 + tn * 4;
    float4 bb1 = *(const float4*)(bih + gc);
    float4 bb2 = *(const float4*)(bhh + gc);
    float bx = bb1.x + bb2.x, by = bb1.y + bb2.y, bz = bb1.z + bb2.z, bw = bb1.w + bb2.w;
    float* op = xg + ((size_t)dir << 24) + (size_t)(m0 + tm * 4) * 4096 + gc;
    #pragma unroll
    for (int i = 0; i < 4; ++i) {
        float4 v;
        v.x = acc[i][0] + bx; v.y = acc[i][1] + by;
        v.z = acc[i][2] + bz; v.w = acc[i][3] + bw;
        *(float4*)(op + (size_t)i * 4096) = v;
    }
}

// ---------------- Phase 2: persistent recurrence, register-resident Whh
__global__ __attribute__((amdgpu_flat_work_group_size(NTHR, NTHR)))
           __attribute__((amdgpu_waves_per_eu(2, 2)))
void bilstm_rec(const float* __restrict__ xg,
                const float* __restrict__ Whh_f, const float* __restrict__ Whh_b,
                u64* hpack)
{
    const int tid = threadIdx.x;
    const int blk = blockIdx.x;
    const int dir = blk >> 7;
    const int lb  = blk & 127;
    const int u0  = lb * 8;
    const int w   = tid >> 6;      // wave index -> unit u0+w
    const int l   = tid & 63;
    const int q   = l >> 4;        // gate 0..3 (i,f,g,o)
    const int kc  = l & 15;        // k-chunk: owns h[64kc .. 64kc+64) for gate q
    const int unit = u0 + w;
    const int grow = q * HID + unit;

    const float* Whh = dir ? Whh_b : Whh_f;
    const float* xgd = xg + ((size_t)dir << 24);
    u64* hp = hpack + (size_t)dir * 2 * HID;

    __shared__ __align__(16) float lds_h[2][16 * PAD];

    // ---- one-time: 16 NAMED float4 weight fragments (64 floats, one gate row chunk)
    const float* wp = Whh + (size_t)grow * HID + kc * 64;
    float4 w0 = *(const float4*)(wp + 0),  w1 = *(const float4*)(wp + 4);
    float4 w2 = *(const float4*)(wp + 8),  w3 = *(const float4*)(wp + 12);
    float4 w4 = *(const float4*)(wp + 16), w5 = *(const float4*)(wp + 20);
    float4 w6 = *(const float4*)(wp + 24), w7 = *(const float4*)(wp + 28);
    float4 w8 = *(const float4*)(wp + 32), w9 = *(const float4*)(wp + 36);
    float4 wa = *(const float4*)(wp + 40), wb = *(const float4*)(wp + 44);
    float4 wc = *(const float4*)(wp + 48), wd = *(const float4*)(wp + 52);
    float4 we = *(const float4*)(wp + 56), wf = *(const float4*)(wp + 60);
    PIN4(w0); PIN4(w1); PIN4(w2); PIN4(w3);
    PIN4(w4); PIN4(w5); PIN4(w6); PIN4(w7);
    PIN4(w8); PIN4(w9); PIN4(wa); PIN4(wb);
    PIN4(wc); PIN4(wd); PIN4(we); PIN4(wf);

    // activation constants: tanh(x) = 2*sigmoid(2x)-1 -> uniform sigmoid chain
    const float a_scl = (q == 2) ? 2.0f : 1.0f;
    const float a_mul = (q == 2) ? 2.0f : 1.0f;
    const float a_add = (q == 2) ? -1.0f : 0.0f;

    float c_state = 0.0f;          // lane 0 of each wave
    float xgv = 0.0f, xgn = 0.0f;  // current / prefetched next (kc==0 lanes)
    if (kc == 0) xgv = xgd[grow];  // t=0 row

    bool dead = false;

    for (int t = 0; t < T_SEQ; ++t) {
        float s = 0.0f;

        if (t > 0) {
            // ---- 2-deep pipelined poll of both packed words ----
            const int b = (t - 1) & 1;
            u64* src = hp + (size_t)b * HID;
            const int k0 = tid * 2;
            u64 e0 = 0, e1 = 0;
            if (!dead) {
                u64 a0 = __hip_atomic_load(src + k0,     __ATOMIC_RELAXED,
                                           __HIP_MEMORY_SCOPE_AGENT);
                u64 a1 = __hip_atomic_load(src + k0 + 1, __ATOMIC_RELAXED,
                                           __HIP_MEMORY_SCOPE_AGENT);
                int sp = 0;
                for (;;) {
                    // issue next sample BEFORE checking current one
                    u64 b0 = __hip_atomic_load(src + k0,     __ATOMIC_RELAXED,
                                               __HIP_MEMORY_SCOPE_AGENT);
                    u64 b1 = __hip_atomic_load(src + k0 + 1, __ATOMIC_RELAXED,
                                               __HIP_MEMORY_SCOPE_AGENT);
                    if (((unsigned)(a0 >> 32) == (unsigned)t) &
                        ((unsigned)(a1 >> 32) == (unsigned)t)) break;
                    a0 = b0; a1 = b1;
                    if (++sp > (1 << 22)) { dead = true; break; }
                }
                e0 = a0; e1 = a1;
            }
            // PAD-68 layout: word k -> lds[(k>>6)*PAD + (k&63)]  (0 conflicts)
            float2 hv;
            hv.x = __uint_as_float((unsigned)(e0 & 0xffffffffu));
            hv.y = __uint_as_float((unsigned)(e1 & 0xffffffffu));
            *(float2*)&lds_h[b][(k0 >> 6) * PAD + (k0 & 63)] = hv;

            // ---- unpinned xg prefetch for t+1 (covered by compute below) ----
            if (kc == 0 && t + 1 < T_SEQ)
                xgn = xgd[(size_t)(t + 1) * 4096 + grow];

            // ---- raw barrier: drain LDS only; polls/prefetch stay in flight ----
            asm volatile("s_waitcnt lgkmcnt(0)\n\ts_barrier" ::: "memory");

            // ---- 16 b128 reads of this lane's 64-float h chunk ----
            const float* lh = &lds_h[b][kc * PAD];
            float4 h0 = *(const float4*)(lh + 0),  h1 = *(const float4*)(lh + 4);
            float4 h2 = *(const float4*)(lh + 8),  h3 = *(const float4*)(lh + 12);
            float4 h4 = *(const float4*)(lh + 16), h5 = *(const float4*)(lh + 20);
            float4 h6 = *(const float4*)(lh + 24), h7 = *(const float4*)(lh + 28);
            s  = DOT4(w0,h0) + DOT4(w1,h1) + DOT4(w2,h2) + DOT4(w3,h3);
            s += DOT4(w4,h4) + DOT4(w5,h5) + DOT4(w6,h6) + DOT4(w7,h7);
            float4 h8 = *(const float4*)(lh + 32), h9 = *(const float4*)(lh + 36);
            float4 ha = *(const float4*)(lh + 40), hb = *(const float4*)(lh + 44);
            float4 hc = *(const float4*)(lh + 48), hd = *(const float4*)(lh + 52);
            float4 he = *(const float4*)(lh + 56), hf = *(const float4*)(lh + 60);
            s += DOT4(w8,h8) + DOT4(w9,h9) + DOT4(wa,ha) + DOT4(wb,hb);
            s += DOT4(wc,hc) + DOT4(wd,hd) + DOT4(we,he) + DOT4(wf,hf);
        } else {
            if (kc == 0) xgn = xgd[(size_t)1 * 4096 + grow];
        }

        // ---- reduce over the 16 kc lanes (4-stage chain) ----
        s += __shfl_xor(s, 1);
        s += __shfl_xor(s, 2);
        s += __shfl_xor(s, 4);
        s += __shfl_xor(s, 8);

        // kc==0 lanes (l = 0,16,32,48) hold gate preacts; activate in parallel
        float pg = s + xgv;
        float act = a_mul * fast_sigmoid(a_scl * pg) + a_add;

        // gather activated gates to lane 0
        float sf = __shfl(act, 16);
        float tg = __shfl(act, 32);
        float so = __shfl(act, 48);

        if (l == 0) {
            float si = act;
            c_state = sf * c_state + si * tg;
            float hval = so * fast_tanh(c_state);
            u64 pk = ((u64)(unsigned)(t + 1) << 32) | (u64)__float_as_uint(hval);
            __hip_atomic_store(hp + (size_t)(t & 1) * HID + unit, pk,
                               __ATOMIC_RELAXED, __HIP_MEMORY_SCOPE_AGENT);
        }

        xgv = xgn;   // consume prefetched xg row
    }
}

// ---------------- head
__global__ void head_kernel(const float* __restrict__ W_ho,
                            const float* __restrict__ b_ho,
                            const u64* __restrict__ hpack,
                            float* __restrict__ out)
{
    const u64* hf  = hpack + 1 * HID;            // dir0 buf1
    const u64* hbk = hpack + 2 * HID + 1 * HID;  // dir1 buf1
    __shared__ float r0[4], r1[4], r2[4];
    int tid = threadIdx.x;  // 256
    float p0 = 0.f, p1 = 0.f, p2 = 0.f;
    for (int i = tid; i < 2 * HID; i += 256) {
        u64 e = (i < HID) ? hf[i] : hbk[i - HID];
        float hv = __uint_as_float((unsigned)(e & 0xffffffffu));
        p0 += W_ho[0 * 2 * HID + i] * hv;
        p1 += W_ho[1 * 2 * HID + i] * hv;
        p2 += W_ho[2 * 2 * HID + i] * hv;
    }
    #pragma unroll
    for (int m = 1; m < 64; m <<= 1) {
        p0 += __shfl_xor(p0, m);
        p1 += __shfl_xor(p1, m);
        p2 += __shfl_xor(p2, m);
    }
    int w = tid >> 6;
    if ((tid & 63) == 0) { r0[w] = p0; r1[w] = p1; r2[w] = p2; }
    __syncthreads();
    if (tid == 0) {
        out[0] = b_ho[0] + r0[0] + r0[1] + r0[2] + r0[3];
        out[1] = b_ho[1] + r1[0] + r1[1] + r1[2] + r1[3];
        out[2] = b_ho[2] + r2[0] + r2[1] + r2[2] + r2[3];
    }
}

extern "C" void kernel_launch(void* const* d_in, const int* in_sizes, int n_in,
                              void* d_out, int out_size, void* d_ws, size_t ws_size,
                              hipStream_t stream) {
    const float* x     = (const float*)d_in[0];
    const float* Wih_f = (const float*)d_in[1];
    const float* Whh_f = (const float*)d_in[2];
    const float* bih_f = (const float*)d_in[3];
    const float* bhh_f = (const float*)d_in[4];
    const float* Wih_b = (const float*)d_in[5];
    const float* Whh_b = (const float*)d_in[6];
    const float* bih_b = (const float*)d_in[7];
    const float* bhh_b = (const float*)d_in[8];
    const float* W_ho  = (const float*)d_in[9];
    const float* b_ho  = (const float*)d_in[10];

    u64* hpack = (u64*)d_ws;                       // 32 KB packed (tag|h)
    float* xg = (float*)((char*)d_ws + 32768);     // 128 MB xg buffer

    // zero tags every call (ws poisoned once, never re-poisoned between replays)
    hipMemsetAsync(d_ws, 0, 2 * 2 * HID * sizeof(u64), stream);

    dim3 gg(4096 / GN, T_SEQ / GM, 2);
    xproj_gemm<<<gg, 256, 0, stream>>>(x, Wih_f, bih_f, bhh_f,
                                       Wih_b, bih_b, bhh_b, xg);
    bilstm_rec<<<NB_TOT, NTHR, 0, stream>>>(xg, Whh_f, Whh_b, hpack);
    head_kernel<<<1, 256, 0, stream>>>(W_ho, b_ho, hpack, (float*)d_out);
}

// Round 10
// 13065.498 us; speedup vs baseline: 1.5385x; 1.5385x over previous
//
#include <hip/hip_runtime.h>
#include <stdint.h>

// Bidirectional LSTM T=4096, B=1, I=H=1024 -> 3 classes.
// R10: R8 poll (fused single-sample + s_sleep backoff -- R9's pipelined poll
//      doubled fabric traffic and added a detect lag; reverted) while keeping
//      R9's two good pieces: raw lgkmcnt-only barrier (no vmcnt(0) drain) and
//      unpinned 1-step-ahead xg prefetch consumed at next use.

#define T_SEQ 4096
#define ISZ   1024
#define HID   1024
#define NB_TOT 256
#define NTHR  512
#define PAD   68

typedef unsigned long long u64;

__device__ __forceinline__ float fast_sigmoid(float x) {
    return 1.0f / (1.0f + __expf(-x));
}
__device__ __forceinline__ float fast_tanh(float x) {
    return 1.0f - 2.0f / (__expf(2.0f * x) + 1.0f);
}

#define PIN4(v) asm volatile("" : "+v"(v.x), "+v"(v.y), "+v"(v.z), "+v"(v.w))
#define DOT4(a, b) ((a).x*(b).x + (a).y*(b).y + (a).z*(b).z + (a).w*(b).w)

// ---------------- Phase 1: xg[dir][t][g] = dot(x[row(t)], Wih[g]) + bih[g] + bhh[g]
#define GM 64
#define GN 64
#define GK 32

__global__ __launch_bounds__(256)
void xproj_gemm(const float* __restrict__ x,
                const float* __restrict__ Wih_f, const float* __restrict__ bih_f,
                const float* __restrict__ bhh_f,
                const float* __restrict__ Wih_b, const float* __restrict__ bih_b,
                const float* __restrict__ bhh_b,
                float* __restrict__ xg)
{
    const int dir = blockIdx.z;
    const float* Wih = dir ? Wih_b : Wih_f;
    const float* bih = dir ? bih_b : bih_f;
    const float* bhh = dir ? bhh_b : bhh_f;
    const int m0 = blockIdx.y * GM;
    const int n0 = blockIdx.x * GN;
    const int tid = threadIdx.x;
    const int ms = tid >> 2;
    const int kq = tid & 3;
    const int tm = tid >> 4;
    const int tn = tid & 15;

    __shared__ float As[GK][GM + 4];
    __shared__ float Bs[GK][GN + 4];

    float acc[4][4] = {};

    const int mrow = m0 + ms;
    const int xrow = dir ? (T_SEQ - 1 - mrow) : mrow;
    const float* ap = x + (size_t)xrow * ISZ + kq * 8;
    const float* bp = Wih + (size_t)(n0 + ms) * ISZ + kq * 8;

    for (int k0 = 0; k0 < ISZ; k0 += GK) {
        float4 a0 = *(const float4*)(ap + k0);
        float4 a1 = *(const float4*)(ap + k0 + 4);
        float4 b0 = *(const float4*)(bp + k0);
        float4 b1 = *(const float4*)(bp + k0 + 4);
        __syncthreads();
        const int kb = kq * 8;
        As[kb+0][ms]=a0.x; As[kb+1][ms]=a0.y; As[kb+2][ms]=a0.z; As[kb+3][ms]=a0.w;
        As[kb+4][ms]=a1.x; As[kb+5][ms]=a1.y; As[kb+6][ms]=a1.z; As[kb+7][ms]=a1.w;
        Bs[kb+0][ms]=b0.x; Bs[kb+1][ms]=b0.y; Bs[kb+2][ms]=b0.z; Bs[kb+3][ms]=b0.w;
        Bs[kb+4][ms]=b1.x; Bs[kb+5][ms]=b1.y; Bs[kb+6][ms]=b1.z; Bs[kb+7][ms]=b1.w;
        __syncthreads();
        #pragma unroll
        for (int k = 0; k < GK; ++k) {
            float4 av = *(const float4*)&As[k][tm * 4];
            float4 bv = *(const float4*)&Bs[k][tn * 4];
            acc[0][0] += av.x*bv.x; acc[0][1] += av.x*bv.y; acc[0][2] += av.x*bv.z; acc[0][3] += av.x*bv.w;
            acc[1][0] += av.y*bv.x; acc[1][1] += av.y*bv.y; acc[1][2] += av.y*bv.z; acc[1][3] += av.y*bv.w;
            acc[2][0] += av.z*bv.x; acc[2][1] += av.z*bv.y; acc[2][2] += av.z*bv.z; acc[2][3] += av.z*bv.w;
            acc[3][0] += av.w*bv.x; acc[3][1] += av.w*bv.y; acc[3][2] += av.w*bv.z; acc[3][3] += av.w*bv.w;
        }
    }

    const int gc = n0 + tn * 4;
    float4 bb1 = *(const float4*)(bih + gc);
    float4 bb2 = *(const float4*)(bhh + gc);
    float bx = bb1.x + bb2.x, by = bb1.y + bb2.y, bz = bb1.z + bb2.z, bw = bb1.w + bb2.w;
    float* op = xg + ((size_t)dir << 24) + (size_t)(m0 + tm * 4) * 4096 + gc;
    #pragma unroll
    for (int i = 0; i < 4; ++i) {
        float4 v;
        v.x = acc[i][0] + bx; v.y = acc[i][1] + by;
        v.z = acc[i][2] + bz; v.w = acc[i][3] + bw;
        *(float4*)(op + (size_t)i * 4096) = v;
    }
}

// ---------------- Phase 2: persistent recurrence, register-resident Whh
__global__ __attribute__((amdgpu_flat_work_group_size(NTHR, NTHR)))
           __attribute__((amdgpu_waves_per_eu(2, 2)))
void bilstm_rec(const float* __restrict__ xg,
                const float* __restrict__ Whh_f, const float* __restrict__ Whh_b,
                u64* hpack)
{
    const int tid = threadIdx.x;
    const int blk = blockIdx.x;
    const int dir = blk >> 7;
    const int lb  = blk & 127;
    const int u0  = lb * 8;
    const int w   = tid >> 6;      // wave index -> unit u0+w
    const int l   = tid & 63;
    const int q   = l >> 4;        // gate 0..3 (i,f,g,o)
    const int kc  = l & 15;        // k-chunk: owns h[64kc .. 64kc+64) for gate q
    const int unit = u0 + w;
    const int grow = q * HID + unit;

    const float* Whh = dir ? Whh_b : Whh_f;
    const float* xgd = xg + ((size_t)dir << 24);
    u64* hp = hpack + (size_t)dir * 2 * HID;

    __shared__ __align__(16) float lds_h[2][16 * PAD];

    // ---- one-time: 16 NAMED float4 weight fragments (64 floats, one gate row chunk)
    const float* wp = Whh + (size_t)grow * HID + kc * 64;
    float4 w0 = *(const float4*)(wp + 0),  w1 = *(const float4*)(wp + 4);
    float4 w2 = *(const float4*)(wp + 8),  w3 = *(const float4*)(wp + 12);
    float4 w4 = *(const float4*)(wp + 16), w5 = *(const float4*)(wp + 20);
    float4 w6 = *(const float4*)(wp + 24), w7 = *(const float4*)(wp + 28);
    float4 w8 = *(const float4*)(wp + 32), w9 = *(const float4*)(wp + 36);
    float4 wa = *(const float4*)(wp + 40), wb = *(const float4*)(wp + 44);
    float4 wc = *(const float4*)(wp + 48), wd = *(const float4*)(wp + 52);
    float4 we = *(const float4*)(wp + 56), wf = *(const float4*)(wp + 60);
    PIN4(w0); PIN4(w1); PIN4(w2); PIN4(w3);
    PIN4(w4); PIN4(w5); PIN4(w6); PIN4(w7);
    PIN4(w8); PIN4(w9); PIN4(wa); PIN4(wb);
    PIN4(wc); PIN4(wd); PIN4(we); PIN4(wf);

    // activation constants: tanh(x) = 2*sigmoid(2x)-1 -> uniform sigmoid chain
    const float a_scl = (q == 2) ? 2.0f : 1.0f;
    const float a_mul = (q == 2) ? 2.0f : 1.0f;
    const float a_add = (q == 2) ? -1.0f : 0.0f;

    float c_state = 0.0f;          // lane 0 of each wave
    float xgv = 0.0f, xgn = 0.0f;  // current / prefetched next (kc==0 lanes)
    if (kc == 0) {
        xgv = xgd[grow];                               // t=0
        xgn = xgd[(size_t)1 * 4096 + grow];            // t=1 prefetch
    }

    bool dead = false;

    for (int t = 0; t < T_SEQ; ++t) {
        float s = 0.0f;

        if (t > 0) {
            // ---- fused single-sample poll of both packed words + s_sleep ----
            const int b = (t - 1) & 1;
            u64* src = hp + (size_t)b * HID;
            const int k0 = tid * 2;
            u64 e0 = 0, e1 = 0;
            if (!dead) {
                int sp = 0;
                for (;;) {
                    e0 = __hip_atomic_load(src + k0,     __ATOMIC_RELAXED,
                                           __HIP_MEMORY_SCOPE_AGENT);
                    e1 = __hip_atomic_load(src + k0 + 1, __ATOMIC_RELAXED,
                                           __HIP_MEMORY_SCOPE_AGENT);
                    if (((unsigned)(e0 >> 32) == (unsigned)t) &
                        ((unsigned)(e1 >> 32) == (unsigned)t)) break;
                    if (++sp > (1 << 21)) { dead = true; break; }
                    __builtin_amdgcn_s_sleep(1);
                }
            }
            // PAD-68 layout: word k -> lds[(k>>6)*PAD + (k&63)]  (0 conflicts)
            float2 hv;
            hv.x = __uint_as_float((unsigned)(e0 & 0xffffffffu));
            hv.y = __uint_as_float((unsigned)(e1 & 0xffffffffu));
            *(float2*)&lds_h[b][(k0 >> 6) * PAD + (k0 & 63)] = hv;

            // ---- unpinned xg prefetch for t+1 (latency covered by compute) ----
            if (kc == 0 && t + 1 < T_SEQ)
                xgn = xgd[(size_t)(t + 1) * 4096 + grow];

            // ---- raw barrier: drain LDS only; prefetch stays in flight ----
            asm volatile("s_waitcnt lgkmcnt(0)\n\ts_barrier" ::: "memory");

            // ---- 16 b128 reads of this lane's 64-float h chunk ----
            const float* lh = &lds_h[b][kc * PAD];
            float4 h0 = *(const float4*)(lh + 0),  h1 = *(const float4*)(lh + 4);
            float4 h2 = *(const float4*)(lh + 8),  h3 = *(const float4*)(lh + 12);
            float4 h4 = *(const float4*)(lh + 16), h5 = *(const float4*)(lh + 20);
            float4 h6 = *(const float4*)(lh + 24), h7 = *(const float4*)(lh + 28);
            s  = DOT4(w0,h0) + DOT4(w1,h1) + DOT4(w2,h2) + DOT4(w3,h3);
            s += DOT4(w4,h4) + DOT4(w5,h5) + DOT4(w6,h6) + DOT4(w7,h7);
            float4 h8 = *(const float4*)(lh + 32), h9 = *(const float4*)(lh + 36);
            float4 ha = *(const float4*)(lh + 40), hb = *(const float4*)(lh + 44);
            float4 hc = *(const float4*)(lh + 48), hd = *(const float4*)(lh + 52);
            float4 he = *(const float4*)(lh + 56), hf = *(const float4*)(lh + 60);
            s += DOT4(w8,h8) + DOT4(w9,h9) + DOT4(wa,ha) + DOT4(wb,hb);
            s += DOT4(wc,hc) + DOT4(wd,hd) + DOT4(we,he) + DOT4(wf,hf);
        }

        // ---- reduce over the 16 kc lanes (4-stage chain) ----
        s += __shfl_xor(s, 1);
        s += __shfl_xor(s, 2);
        s += __shfl_xor(s, 4);
        s += __shfl_xor(s, 8);

        // kc==0 lanes (l = 0,16,32,48) hold gate preacts; activate in parallel
        float pg = s + xgv;
        float act = a_mul * fast_sigmoid(a_scl * pg) + a_add;

        // gather activated gates to lane 0
        float sf = __shfl(act, 16);
        float tg = __shfl(act, 32);
        float so = __shfl(act, 48);

        if (l == 0) {
            float si = act;
            c_state = sf * c_state + si * tg;
            float hval = so * fast_tanh(c_state);
            u64 pk = ((u64)(unsigned)(t + 1) << 32) | (u64)__float_as_uint(hval);
            __hip_atomic_store(hp + (size_t)(t & 1) * HID + unit, pk,
                               __ATOMIC_RELAXED, __HIP_MEMORY_SCOPE_AGENT);
        }

        xgv = xgn;   // consume prefetched xg row
    }
}

// ---------------- head
__global__ void head_kernel(const float* __restrict__ W_ho,
                            const float* __restrict__ b_ho,
                            const u64* __restrict__ hpack,
                            float* __restrict__ out)
{
    const u64* hf  = hpack + 1 * HID;            // dir0 buf1
    const u64* hbk = hpack + 2 * HID + 1 * HID;  // dir1 buf1
    __shared__ float r0[4], r1[4], r2[4];
    int tid = threadIdx.x;  // 256
    float p0 = 0.f, p1 = 0.f, p2 = 0.f;
    for (int i = tid; i < 2 * HID; i += 256) {
        u64 e = (i < HID) ? hf[i] : hbk[i - HID];
        float hv = __uint_as_float((unsigned)(e & 0xffffffffu));
        p0 += W_ho[0 * 2 * HID + i] * hv;
        p1 += W_ho[1 * 2 * HID + i] * hv;
        p2 += W_ho[2 * 2 * HID + i] * hv;
    }
    #pragma unroll
    for (int m = 1; m < 64; m <<= 1) {
        p0 += __shfl_xor(p0, m);
        p1 += __shfl_xor(p1, m);
        p2 += __shfl_xor(p2, m);
    }
    int w = tid >> 6;
    if ((tid & 63) == 0) { r0[w] = p0; r1[w] = p1; r2[w] = p2; }
    __syncthreads();
    if (tid == 0) {
        out[0] = b_ho[0] + r0[0] + r0[1] + r0[2] + r0[3];
        out[1] = b_ho[1] + r1[0] + r1[1] + r1[2] + r1[3];
        out[2] = b_ho[2] + r2[0] + r2[1] + r2[2] + r2[3];
    }
}

extern "C" void kernel_launch(void* const* d_in, const int* in_sizes, int n_in,
                              void* d_out, int out_size, void* d_ws, size_t ws_size,
                              hipStream_t stream) {
    const float* x     = (const float*)d_in[0];
    const float* Wih_f = (const float*)d_in[1];
    const float* Whh_f = (const float*)d_in[2];
    const float* bih_f = (const float*)d_in[3];
    const float* bhh_f = (const float*)d_in[4];
    const float* Wih_b = (const float*)d_in[5];
    const float* Whh_b = (const float*)d_in[6];
    const float* bih_b = (const float*)d_in[7];
    const float* bhh_b = (const float*)d_in[8];
    const float* W_ho  = (const float*)d_in[9];
    const float* b_ho  = (const float*)d_in[10];

    u64* hpack = (u64*)d_ws;                       // 32 KB packed (tag|h)
    float* xg = (float*)((char*)d_ws + 32768);     // 128 MB xg buffer

    // zero tags every call (ws poisoned once, never re-poisoned between replays)
    hipMemsetAsync(d_ws, 0, 2 * 2 * HID * sizeof(u64), stream);

    dim3 gg(4096 / GN, T_SEQ / GM, 2);
    xproj_gemm<<<gg, 256, 0, stream>>>(x, Wih_f, bih_f, bhh_f,
                                       Wih_b, bih_b, bhh_b, xg);
    bilstm_rec<<<NB_TOT, NTHR, 0, stream>>>(xg, Whh_f, Whh_b, hpack);
    head_kernel<<<1, 256, 0, stream>>>(W_ho, b_ho, hpack, (float*)d_out);
}

// Round 11
// 9233.198 us; speedup vs baseline: 2.1771x; 1.4151x over previous
//
#include <hip/hip_runtime.h>
#include <stdint.h>

// Bidirectional LSTM T=4096, B=1, I=H=1024 -> 3 classes.
// R11: exact R8 structure (proven 7.35ms: __syncthreads barrier, fused
//      single-sample poll + s_sleep, pinned loop-end xg prefetch) with ONE
//      structural change: 2 units per wave -> 64 blocks/dir (128 total).
//      Halves chip-wide poll population (R9 proved poll traffic contends
//      with publish visibility), doubles per-step compute under the same
//      sync umbrella, publishes 2 adjacent u64 per wave.

#define T_SEQ 4096
#define ISZ   1024
#define HID   1024
#define NB_TOT 128
#define NTHR  512
#define PAD   68

typedef unsigned long long u64;

__device__ __forceinline__ float fast_sigmoid(float x) {
    return 1.0f / (1.0f + __expf(-x));
}
__device__ __forceinline__ float fast_tanh(float x) {
    return 1.0f - 2.0f / (__expf(2.0f * x) + 1.0f);
}

#define PIN4(v) asm volatile("" : "+v"(v.x), "+v"(v.y), "+v"(v.z), "+v"(v.w))
#define DOT4(a, b) ((a).x*(b).x + (a).y*(b).y + (a).z*(b).z + (a).w*(b).w)

// ---------------- Phase 1: xg[dir][t][g] = dot(x[row(t)], Wih[g]) + bih[g] + bhh[g]
#define GM 64
#define GN 64
#define GK 32

__global__ __launch_bounds__(256)
void xproj_gemm(const float* __restrict__ x,
                const float* __restrict__ Wih_f, const float* __restrict__ bih_f,
                const float* __restrict__ bhh_f,
                const float* __restrict__ Wih_b, const float* __restrict__ bih_b,
                const float* __restrict__ bhh_b,
                float* __restrict__ xg)
{
    const int dir = blockIdx.z;
    const float* Wih = dir ? Wih_b : Wih_f;
    const float* bih = dir ? bih_b : bih_f;
    const float* bhh = dir ? bhh_b : bhh_f;
    const int m0 = blockIdx.y * GM;
    const int n0 = blockIdx.x * GN;
    const int tid = threadIdx.x;
    const int ms = tid >> 2;
    const int kq = tid & 3;
    const int tm = tid >> 4;
    const int tn = tid & 15;

    __shared__ float As[GK][GM + 4];
    __shared__ float Bs[GK][GN + 4];

    float acc[4][4] = {};

    const int mrow = m0 + ms;
    const int xrow = dir ? (T_SEQ - 1 - mrow) : mrow;
    const float* ap = x + (size_t)xrow * ISZ + kq * 8;
    const float* bp = Wih + (size_t)(n0 + ms) * ISZ + kq * 8;

    for (int k0 = 0; k0 < ISZ; k0 += GK) {
        float4 a0 = *(const float4*)(ap + k0);
        float4 a1 = *(const float4*)(ap + k0 + 4);
        float4 b0 = *(const float4*)(bp + k0);
        float4 b1 = *(const float4*)(bp + k0 + 4);
        __syncthreads();
        const int kb = kq * 8;
        As[kb+0][ms]=a0.x; As[kb+1][ms]=a0.y; As[kb+2][ms]=a0.z; As[kb+3][ms]=a0.w;
        As[kb+4][ms]=a1.x; As[kb+5][ms]=a1.y; As[kb+6][ms]=a1.z; As[kb+7][ms]=a1.w;
        Bs[kb+0][ms]=b0.x; Bs[kb+1][ms]=b0.y; Bs[kb+2][ms]=b0.z; Bs[kb+3][ms]=b0.w;
        Bs[kb+4][ms]=b1.x; Bs[kb+5][ms]=b1.y; Bs[kb+6][ms]=b1.z; Bs[kb+7][ms]=b1.w;
        __syncthreads();
        #pragma unroll
        for (int k = 0; k < GK; ++k) {
            float4 av = *(const float4*)&As[k][tm * 4];
            float4 bv = *(const float4*)&Bs[k][tn * 4];
            acc[0][0] += av.x*bv.x; acc[0][1] += av.x*bv.y; acc[0][2] += av.x*bv.z; acc[0][3] += av.x*bv.w;
            acc[1][0] += av.y*bv.x; acc[1][1] += av.y*bv.y; acc[1][2] += av.y*bv.z; acc[1][3] += av.y*bv.w;
            acc[2][0] += av.z*bv.x; acc[2][1] += av.z*bv.y; acc[2][2] += av.z*bv.z; acc[2][3] += av.z*bv.w;
            acc[3][0] += av.w*bv.x; acc[3][1] += av.w*bv.y; acc[3][2] += av.w*bv.z; acc[3][3] += av.w*bv.w;
        }
    }

    const int gc = n0 + tn * 4;
    float4 bb1 = *(const float4*)(bih + gc);
    float4 bb2 = *(const float4*)(bhh + gc);
    float bx = bb1.x + bb2.x, by = bb1.y + bb2.y, bz = bb1.z + bb2.z, bw = bb1.w + bb2.w;
    float* op = xg + ((size_t)dir << 24) + (size_t)(m0 + tm * 4) * 4096 + gc;
    #pragma unroll
    for (int i = 0; i < 4; ++i) {
        float4 v;
        v.x = acc[i][0] + bx; v.y = acc[i][1] + by;
        v.z = acc[i][2] + bz; v.w = acc[i][3] + bw;
        *(float4*)(op + (size_t)i * 4096) = v;
    }
}

// ---------------- Phase 2: persistent recurrence, 2 units/wave, resident Whh
__global__ __attribute__((amdgpu_flat_work_group_size(NTHR, NTHR)))
           __attribute__((amdgpu_waves_per_eu(2, 2)))
void bilstm_rec(const float* __restrict__ xg,
                const float* __restrict__ Whh_f, const float* __restrict__ Whh_b,
                u64* hpack)
{
    const int tid = threadIdx.x;
    const int blk = blockIdx.x;
    const int dir = blk >> 6;          // 64 blocks per direction
    const int lb  = blk & 63;
    const int u0  = lb * 16;
    const int w   = tid >> 6;          // wave -> units uA, uB
    const int l   = tid & 63;
    const int q   = l >> 4;            // gate 0..3 (i,f,g,o)
    const int kc  = l & 15;            // k-chunk: h[64kc .. 64kc+64)
    const int uA  = u0 + 2 * w;
    const int growA = q * HID + uA;    // unit B row = growA + 1 -> +HID floats

    const float* Whh = dir ? Whh_b : Whh_f;
    const float* xgd = xg + ((size_t)dir << 24);
    u64* hp = hpack + (size_t)dir * 2 * HID;

    __shared__ __align__(16) float lds_h[2][16 * PAD];

    // ---- one-time: 32 NAMED float4 weight fragments (128 floats, 2 rows) ----
    const float* wpA = Whh + (size_t)growA * HID + kc * 64;
    const float* wpB = wpA + HID;      // next unit, same gate
    float4 a0 = *(const float4*)(wpA + 0),  a1 = *(const float4*)(wpA + 4);
    float4 a2 = *(const float4*)(wpA + 8),  a3 = *(const float4*)(wpA + 12);
    float4 a4 = *(const float4*)(wpA + 16), a5 = *(const float4*)(wpA + 20);
    float4 a6 = *(const float4*)(wpA + 24), a7 = *(const float4*)(wpA + 28);
    float4 a8 = *(const float4*)(wpA + 32), a9 = *(const float4*)(wpA + 36);
    float4 aa = *(const float4*)(wpA + 40), ab = *(const float4*)(wpA + 44);
    float4 ac = *(const float4*)(wpA + 48), ad = *(const float4*)(wpA + 52);
    float4 ae = *(const float4*)(wpA + 56), af = *(const float4*)(wpA + 60);
    float4 b0 = *(const float4*)(wpB + 0),  b1 = *(const float4*)(wpB + 4);
    float4 b2 = *(const float4*)(wpB + 8),  b3 = *(const float4*)(wpB + 12);
    float4 b4 = *(const float4*)(wpB + 16), b5 = *(const float4*)(wpB + 20);
    float4 b6 = *(const float4*)(wpB + 24), b7 = *(const float4*)(wpB + 28);
    float4 b8 = *(const float4*)(wpB + 32), b9 = *(const float4*)(wpB + 36);
    float4 ba = *(const float4*)(wpB + 40), bb = *(const float4*)(wpB + 44);
    float4 bc = *(const float4*)(wpB + 48), bd = *(const float4*)(wpB + 52);
    float4 be = *(const float4*)(wpB + 56), bf = *(const float4*)(wpB + 60);
    PIN4(a0); PIN4(a1); PIN4(a2); PIN4(a3);
    PIN4(a4); PIN4(a5); PIN4(a6); PIN4(a7);
    PIN4(a8); PIN4(a9); PIN4(aa); PIN4(ab);
    PIN4(ac); PIN4(ad); PIN4(ae); PIN4(af);
    PIN4(b0); PIN4(b1); PIN4(b2); PIN4(b3);
    PIN4(b4); PIN4(b5); PIN4(b6); PIN4(b7);
    PIN4(b8); PIN4(b9); PIN4(ba); PIN4(bb);
    PIN4(bc); PIN4(bd); PIN4(be); PIN4(bf);

    // activation constants: tanh(x) = 2*sigmoid(2x)-1 -> uniform sigmoid chain
    const float a_scl = (q == 2) ? 2.0f : 1.0f;
    const float a_mul = (q == 2) ? 2.0f : 1.0f;
    const float a_add = (q == 2) ? -1.0f : 0.0f;

    float cA = 0.0f, cB = 0.0f;        // lane 0 of each wave
    float xgvA = 0.0f, xgvB = 0.0f;    // kc==0 lanes carry gate q's bias+x proj
    if (kc == 0) {
        xgvA = xgd[growA];
        xgvB = xgd[growA + 1];
    }
    asm volatile("" : "+v"(xgvA), "+v"(xgvB));

    bool dead = false;

    for (int t = 0; t < T_SEQ; ++t) {
        float sA = 0.0f, sB = 0.0f;

        if (t > 0) {
            // ---- fused single-sample poll of both packed words + s_sleep ----
            const int b = (t - 1) & 1;
            u64* src = hp + (size_t)b * HID;
            const int k0 = tid * 2;
            u64 e0 = 0, e1 = 0;
            if (!dead) {
                int sp = 0;
                for (;;) {
                    e0 = __hip_atomic_load(src + k0,     __ATOMIC_RELAXED,
                                           __HIP_MEMORY_SCOPE_AGENT);
                    e1 = __hip_atomic_load(src + k0 + 1, __ATOMIC_RELAXED,
                                           __HIP_MEMORY_SCOPE_AGENT);
                    if (((unsigned)(e0 >> 32) == (unsigned)t) &
                        ((unsigned)(e1 >> 32) == (unsigned)t)) break;
                    if (++sp > (1 << 21)) { dead = true; break; }
                    __builtin_amdgcn_s_sleep(1);
                }
            }
            // PAD-68 layout: word k -> lds[(k>>6)*PAD + (k&63)]  (0 conflicts)
            float2 hv;
            hv.x = __uint_as_float((unsigned)(e0 & 0xffffffffu));
            hv.y = __uint_as_float((unsigned)(e1 & 0xffffffffu));
            *(float2*)&lds_h[b][(k0 >> 6) * PAD + (k0 & 63)] = hv;
            __syncthreads();

            // ---- 16 b128 reads of this lane's 64-float h chunk; dot vs 2 rows
            const float* lh = &lds_h[b][kc * PAD];
            float4 h0 = *(const float4*)(lh + 0),  h1 = *(const float4*)(lh + 4);
            float4 h2 = *(const float4*)(lh + 8),  h3 = *(const float4*)(lh + 12);
            float4 h4 = *(const float4*)(lh + 16), h5 = *(const float4*)(lh + 20);
            float4 h6 = *(const float4*)(lh + 24), h7 = *(const float4*)(lh + 28);
            sA  = DOT4(a0,h0) + DOT4(a1,h1) + DOT4(a2,h2) + DOT4(a3,h3);
            sA += DOT4(a4,h4) + DOT4(a5,h5) + DOT4(a6,h6) + DOT4(a7,h7);
            sB  = DOT4(b0,h0) + DOT4(b1,h1) + DOT4(b2,h2) + DOT4(b3,h3);
            sB += DOT4(b4,h4) + DOT4(b5,h5) + DOT4(b6,h6) + DOT4(b7,h7);
            float4 h8 = *(const float4*)(lh + 32), h9 = *(const float4*)(lh + 36);
            float4 ha = *(const float4*)(lh + 40), hb = *(const float4*)(lh + 44);
            float4 hc = *(const float4*)(lh + 48), hd = *(const float4*)(lh + 52);
            float4 he = *(const float4*)(lh + 56), hf = *(const float4*)(lh + 60);
            sA += DOT4(a8,h8) + DOT4(a9,h9) + DOT4(aa,ha) + DOT4(ab,hb);
            sA += DOT4(ac,hc) + DOT4(ad,hd) + DOT4(ae,he) + DOT4(af,hf);
            sB += DOT4(b8,h8) + DOT4(b9,h9) + DOT4(ba,ha) + DOT4(bb,hb);
            sB += DOT4(bc,hc) + DOT4(bd,hd) + DOT4(be,he) + DOT4(bf,hf);
        }

        // ---- reduce over the 16 kc lanes (4-stage chain, both units) ----
        sA += __shfl_xor(sA, 1);  sB += __shfl_xor(sB, 1);
        sA += __shfl_xor(sA, 2);  sB += __shfl_xor(sB, 2);
        sA += __shfl_xor(sA, 4);  sB += __shfl_xor(sB, 4);
        sA += __shfl_xor(sA, 8);  sB += __shfl_xor(sB, 8);

        // kc==0 lanes (l = 0,16,32,48) hold gate preacts; activate in parallel
        float actA = a_mul * fast_sigmoid(a_scl * (sA + xgvA)) + a_add;
        float actB = a_mul * fast_sigmoid(a_scl * (sB + xgvB)) + a_add;

        // gather activated gates to lane 0
        float sfA = __shfl(actA, 16), tgA = __shfl(actA, 32), soA = __shfl(actA, 48);
        float sfB = __shfl(actB, 16), tgB = __shfl(actB, 32), soB = __shfl(actB, 48);

        if (l == 0) {
            cA = sfA * cA + actA * tgA;
            float hA = soA * fast_tanh(cA);
            cB = sfB * cB + actB * tgB;
            float hB = soB * fast_tanh(cB);
            u64 pkA = ((u64)(unsigned)(t + 1) << 32) | (u64)__float_as_uint(hA);
            u64 pkB = ((u64)(unsigned)(t + 1) << 32) | (u64)__float_as_uint(hB);
            u64* dst = hp + (size_t)(t & 1) * HID + uA;
            __hip_atomic_store(dst,     pkA, __ATOMIC_RELAXED, __HIP_MEMORY_SCOPE_AGENT);
            __hip_atomic_store(dst + 1, pkB, __ATOMIC_RELAXED, __HIP_MEMORY_SCOPE_AGENT);
        }

        // pinned xg prefetch for t+1 (R8 shape; hides under next poll window)
        if (t + 1 < T_SEQ && kc == 0) {
            xgvA = xgd[(size_t)(t + 1) * 4096 + growA];
            xgvB = xgd[(size_t)(t + 1) * 4096 + growA + 1];
            asm volatile("" : "+v"(xgvA), "+v"(xgvB));
        }
    }
}

// ---------------- head
__global__ void head_kernel(const float* __restrict__ W_ho,
                            const float* __restrict__ b_ho,
                            const u64* __restrict__ hpack,
                            float* __restrict__ out)
{
    const u64* hf  = hpack + 1 * HID;            // dir0 buf1
    const u64* hbk = hpack + 2 * HID + 1 * HID;  // dir1 buf1
    __shared__ float r0[4], r1[4], r2[4];
    int tid = threadIdx.x;  // 256
    float p0 = 0.f, p1 = 0.f, p2 = 0.f;
    for (int i = tid; i < 2 * HID; i += 256) {
        u64 e = (i < HID) ? hf[i] : hbk[i - HID];
        float hv = __uint_as_float((unsigned)(e & 0xffffffffu));
        p0 += W_ho[0 * 2 * HID + i] * hv;
        p1 += W_ho[1 * 2 * HID + i] * hv;
        p2 += W_ho[2 * 2 * HID + i] * hv;
    }
    #pragma unroll
    for (int m = 1; m < 64; m <<= 1) {
        p0 += __shfl_xor(p0, m);
        p1 += __shfl_xor(p1, m);
        p2 += __shfl_xor(p2, m);
    }
    int w = tid >> 6;
    if ((tid & 63) == 0) { r0[w] = p0; r1[w] = p1; r2[w] = p2; }
    __syncthreads();
    if (tid == 0) {
        out[0] = b_ho[0] + r0[0] + r0[1] + r0[2] + r0[3];
        out[1] = b_ho[1] + r1[0] + r1[1] + r1[2] + r1[3];
        out[2] = b_ho[2] + r2[0] + r2[1] + r2[2] + r2[3];
    }
}

extern "C" void kernel_launch(void* const* d_in, const int* in_sizes, int n_in,
                              void* d_out, int out_size, void* d_ws, size_t ws_size,
                              hipStream_t stream) {
    const float* x     = (const float*)d_in[0];
    const float* Wih_f = (const float*)d_in[1];
    const float* Whh_f = (const float*)d_in[2];
    const float* bih_f = (const float*)d_in[3];
    const float* bhh_f = (const float*)d_in[4];
    const float* Wih_b = (const float*)d_in[5];
    const float* Whh_b = (const float*)d_in[6];
    const float* bih_b = (const float*)d_in[7];
    const float* bhh_b = (const float*)d_in[8];
    const float* W_ho  = (const float*)d_in[9];
    const float* b_ho  = (const float*)d_in[10];

    u64* hpack = (u64*)d_ws;                       // 32 KB packed (tag|h)
    float* xg = (float*)((char*)d_ws + 32768);     // 128 MB xg buffer

    // zero tags every call (ws poisoned once, never re-poisoned between replays)
    hipMemsetAsync(d_ws, 0, 2 * 2 * HID * sizeof(u64), stream);

    dim3 gg(4096 / GN, T_SEQ / GM, 2);
    xproj_gemm<<<gg, 256, 0, stream>>>(x, Wih_f, bih_f, bhh_f,
                                       Wih_b, bih_b, bhh_b, xg);
    bilstm_rec<<<NB_TOT, NTHR, 0, stream>>>(xg, Whh_f, Whh_b, hpack);
    head_kernel<<<1, 256, 0, stream>>>(W_ho, b_ho, hpack, (float*)d_out);
}

// Round 12
// 7981.629 us; speedup vs baseline: 2.5185x; 1.1568x over previous
//
#include <hip/hip_runtime.h>
#include <stdint.h>

// Bidirectional LSTM T=4096, B=1, I=H=1024 -> 3 classes.
// R12: byte-exact R8 (proven best, 7.35ms rec) + ONE insertion:
//      s_waitcnt vmcnt(0) immediately after the h publish store.
//      Theory: R8's publish store only drains at the NEXT step's
//      __syncthreads (after poll-detect) -> circular visibility slack.
//      R10 removed that drain entirely and regressed (longer spins),
//      confirming store-drain timing governs detect latency. Flush eagerly.

#define T_SEQ 4096
#define ISZ   1024
#define HID   1024
#define NB_TOT 256
#define NTHR  512
#define PAD   68

typedef unsigned long long u64;

__device__ __forceinline__ float fast_sigmoid(float x) {
    return 1.0f / (1.0f + __expf(-x));
}
__device__ __forceinline__ float fast_tanh(float x) {
    return 1.0f - 2.0f / (__expf(2.0f * x) + 1.0f);
}

#define PIN4(v) asm volatile("" : "+v"(v.x), "+v"(v.y), "+v"(v.z), "+v"(v.w))
#define DOT4(a, b) ((a).x*(b).x + (a).y*(b).y + (a).z*(b).z + (a).w*(b).w)

// ---------------- Phase 1: xg[dir][t][g] = dot(x[row(t)], Wih[g]) + bih[g] + bhh[g]
#define GM 64
#define GN 64
#define GK 32

__global__ __launch_bounds__(256)
void xproj_gemm(const float* __restrict__ x,
                const float* __restrict__ Wih_f, const float* __restrict__ bih_f,
                const float* __restrict__ bhh_f,
                const float* __restrict__ Wih_b, const float* __restrict__ bih_b,
                const float* __restrict__ bhh_b,
                float* __restrict__ xg)
{
    const int dir = blockIdx.z;
    const float* Wih = dir ? Wih_b : Wih_f;
    const float* bih = dir ? bih_b : bih_f;
    const float* bhh = dir ? bhh_b : bhh_f;
    const int m0 = blockIdx.y * GM;
    const int n0 = blockIdx.x * GN;
    const int tid = threadIdx.x;
    const int ms = tid >> 2;
    const int kq = tid & 3;
    const int tm = tid >> 4;
    const int tn = tid & 15;

    __shared__ float As[GK][GM + 4];
    __shared__ float Bs[GK][GN + 4];

    float acc[4][4] = {};

    const int mrow = m0 + ms;
    const int xrow = dir ? (T_SEQ - 1 - mrow) : mrow;
    const float* ap = x + (size_t)xrow * ISZ + kq * 8;
    const float* bp = Wih + (size_t)(n0 + ms) * ISZ + kq * 8;

    for (int k0 = 0; k0 < ISZ; k0 += GK) {
        float4 a0 = *(const float4*)(ap + k0);
        float4 a1 = *(const float4*)(ap + k0 + 4);
        float4 b0 = *(const float4*)(bp + k0);
        float4 b1 = *(const float4*)(bp + k0 + 4);
        __syncthreads();
        const int kb = kq * 8;
        As[kb+0][ms]=a0.x; As[kb+1][ms]=a0.y; As[kb+2][ms]=a0.z; As[kb+3][ms]=a0.w;
        As[kb+4][ms]=a1.x; As[kb+5][ms]=a1.y; As[kb+6][ms]=a1.z; As[kb+7][ms]=a1.w;
        Bs[kb+0][ms]=b0.x; Bs[kb+1][ms]=b0.y; Bs[kb+2][ms]=b0.z; Bs[kb+3][ms]=b0.w;
        Bs[kb+4][ms]=b1.x; Bs[kb+5][ms]=b1.y; Bs[kb+6][ms]=b1.z; Bs[kb+7][ms]=b1.w;
        __syncthreads();
        #pragma unroll
        for (int k = 0; k < GK; ++k) {
            float4 av = *(const float4*)&As[k][tm * 4];
            float4 bv = *(const float4*)&Bs[k][tn * 4];
            acc[0][0] += av.x*bv.x; acc[0][1] += av.x*bv.y; acc[0][2] += av.x*bv.z; acc[0][3] += av.x*bv.w;
            acc[1][0] += av.y*bv.x; acc[1][1] += av.y*bv.y; acc[1][2] += av.y*bv.z; acc[1][3] += av.y*bv.w;
            acc[2][0] += av.z*bv.x; acc[2][1] += av.z*bv.y; acc[2][2] += av.z*bv.z; acc[2][3] += av.z*bv.w;
            acc[3][0] += av.w*bv.x; acc[3][1] += av.w*bv.y; acc[3][2] += av.w*bv.z; acc[3][3] += av.w*bv.w;
        }
    }

    const int gc = n0 + tn * 4;
    float4 bb1 = *(const float4*)(bih + gc);
    float4 bb2 = *(const float4*)(bhh + gc);
    float bx = bb1.x + bb2.x, by = bb1.y + bb2.y, bz = bb1.z + bb2.z, bw = bb1.w + bb2.w;
    float* op = xg + ((size_t)dir << 24) + (size_t)(m0 + tm * 4) * 4096 + gc;
    #pragma unroll
    for (int i = 0; i < 4; ++i) {
        float4 v;
        v.x = acc[i][0] + bx; v.y = acc[i][1] + by;
        v.z = acc[i][2] + bz; v.w = acc[i][3] + bw;
        *(float4*)(op + (size_t)i * 4096) = v;
    }
}

// ---------------- Phase 2: persistent recurrence, register-resident Whh
__global__ __attribute__((amdgpu_flat_work_group_size(NTHR, NTHR)))
           __attribute__((amdgpu_waves_per_eu(2, 2)))
void bilstm_rec(const float* __restrict__ xg,
                const float* __restrict__ Whh_f, const float* __restrict__ Whh_b,
                u64* hpack)
{
    const int tid = threadIdx.x;
    const int blk = blockIdx.x;
    const int dir = blk >> 7;
    const int lb  = blk & 127;
    const int u0  = lb * 8;
    const int w   = tid >> 6;      // wave index -> unit u0+w
    const int l   = tid & 63;
    const int q   = l >> 4;        // gate 0..3 (i,f,g,o)
    const int kc  = l & 15;        // k-chunk: owns h[64kc .. 64kc+64) for gate q
    const int unit = u0 + w;
    const int grow = q * HID + unit;

    const float* Whh = dir ? Whh_b : Whh_f;
    const float* xgd = xg + ((size_t)dir << 24);
    u64* hp = hpack + (size_t)dir * 2 * HID;

    __shared__ __align__(16) float lds_h[2][16 * PAD];

    // ---- one-time: 16 NAMED float4 weight fragments (64 floats, one gate row chunk)
    const float* wp = Whh + (size_t)grow * HID + kc * 64;
    float4 w0 = *(const float4*)(wp + 0),  w1 = *(const float4*)(wp + 4);
    float4 w2 = *(const float4*)(wp + 8),  w3 = *(const float4*)(wp + 12);
    float4 w4 = *(const float4*)(wp + 16), w5 = *(const float4*)(wp + 20);
    float4 w6 = *(const float4*)(wp + 24), w7 = *(const float4*)(wp + 28);
    float4 w8 = *(const float4*)(wp + 32), w9 = *(const float4*)(wp + 36);
    float4 wa = *(const float4*)(wp + 40), wb = *(const float4*)(wp + 44);
    float4 wc = *(const float4*)(wp + 48), wd = *(const float4*)(wp + 52);
    float4 we = *(const float4*)(wp + 56), wf = *(const float4*)(wp + 60);
    PIN4(w0); PIN4(w1); PIN4(w2); PIN4(w3);
    PIN4(w4); PIN4(w5); PIN4(w6); PIN4(w7);
    PIN4(w8); PIN4(w9); PIN4(wa); PIN4(wb);
    PIN4(wc); PIN4(wd); PIN4(we); PIN4(wf);

    // activation constants: tanh(x) = 2*sigmoid(2x)-1 -> uniform sigmoid chain
    const float a_scl = (q == 2) ? 2.0f : 1.0f;
    const float a_mul = (q == 2) ? 2.0f : 1.0f;
    const float a_add = (q == 2) ? -1.0f : 0.0f;

    float c_state = 0.0f;          // lane 0 of each wave
    float xgv = 0.0f;              // kc==0 lanes carry gate q's bias+x proj
    if (kc == 0) xgv = xgd[grow];  // t=0 row
    asm volatile("" : "+v"(xgv));

    bool dead = false;

    for (int t = 0; t < T_SEQ; ++t) {
        float s = 0.0f;

        if (t > 0) {
            // ---- stage h(t-1): fused poll of both packed words, s_sleep backoff
            const int b = (t - 1) & 1;
            u64* src = hp + (size_t)b * HID;
            const int k0 = tid * 2;
            u64 e0 = 0, e1 = 0;
            if (!dead) {
                int sp = 0;
                for (;;) {
                    e0 = __hip_atomic_load(src + k0,     __ATOMIC_RELAXED,
                                           __HIP_MEMORY_SCOPE_AGENT);
                    e1 = __hip_atomic_load(src + k0 + 1, __ATOMIC_RELAXED,
                                           __HIP_MEMORY_SCOPE_AGENT);
                    if (((unsigned)(e0 >> 32) == (unsigned)t) &
                        ((unsigned)(e1 >> 32) == (unsigned)t)) break;
                    if (++sp > (1 << 21)) { dead = true; break; }
                    __builtin_amdgcn_s_sleep(1);
                }
            }
            // PAD-68 layout: word k -> lds[(k>>6)*PAD + (k&63)]  (0 conflicts)
            float2 hv;
            hv.x = __uint_as_float((unsigned)(e0 & 0xffffffffu));
            hv.y = __uint_as_float((unsigned)(e1 & 0xffffffffu));
            *(float2*)&lds_h[b][(k0 >> 6) * PAD + (k0 & 63)] = hv;
            __syncthreads();

            // ---- 16 b128 reads of this lane's 64-float h chunk ----
            const float* lh = &lds_h[b][kc * PAD];
            float4 h0 = *(const float4*)(lh + 0),  h1 = *(const float4*)(lh + 4);
            float4 h2 = *(const float4*)(lh + 8),  h3 = *(const float4*)(lh + 12);
            float4 h4 = *(const float4*)(lh + 16), h5 = *(const float4*)(lh + 20);
            float4 h6 = *(const float4*)(lh + 24), h7 = *(const float4*)(lh + 28);
            s  = DOT4(w0,h0) + DOT4(w1,h1) + DOT4(w2,h2) + DOT4(w3,h3);
            s += DOT4(w4,h4) + DOT4(w5,h5) + DOT4(w6,h6) + DOT4(w7,h7);
            float4 h8 = *(const float4*)(lh + 32), h9 = *(const float4*)(lh + 36);
            float4 ha = *(const float4*)(lh + 40), hb = *(const float4*)(lh + 44);
            float4 hc = *(const float4*)(lh + 48), hd = *(const float4*)(lh + 52);
            float4 he = *(const float4*)(lh + 56), hf = *(const float4*)(lh + 60);
            s += DOT4(w8,h8) + DOT4(w9,h9) + DOT4(wa,ha) + DOT4(wb,hb);
            s += DOT4(wc,hc) + DOT4(wd,hd) + DOT4(we,he) + DOT4(wf,hf);
        }

        // ---- reduce over the 16 kc lanes (4-stage chain) ----
        s += __shfl_xor(s, 1);
        s += __shfl_xor(s, 2);
        s += __shfl_xor(s, 4);
        s += __shfl_xor(s, 8);

        // kc==0 lanes (l = 0,16,32,48) hold gate preacts; activate in parallel
        float pg = s + xgv;
        float act = a_mul * fast_sigmoid(a_scl * pg) + a_add;

        // gather activated gates to lane 0
        float sf = __shfl(act, 16);
        float tg = __shfl(act, 32);
        float so = __shfl(act, 48);

        if (l == 0) {
            float si = act;
            c_state = sf * c_state + si * tg;
            float hval = so * fast_tanh(c_state);
            u64 pk = ((u64)(unsigned)(t + 1) << 32) | (u64)__float_as_uint(hval);
            __hip_atomic_store(hp + (size_t)(t & 1) * HID + unit, pk,
                               __ATOMIC_RELAXED, __HIP_MEMORY_SCOPE_AGENT);
        }
        // R12: eager flush -- force the publish store out to the coherent
        // point NOW instead of at next step's __syncthreads (lazy drain was
        // the visibility lag; R10 proved drain timing governs detect time).
        asm volatile("s_waitcnt vmcnt(0)" ::: "memory");

        // prefetch next xg row (hides under next poll window)
        if (t + 1 < T_SEQ && kc == 0) {
            xgv = xgd[(size_t)(t + 1) * 4096 + grow];
            asm volatile("" : "+v"(xgv));
        }
    }
}

// ---------------- head
__global__ void head_kernel(const float* __restrict__ W_ho,
                            const float* __restrict__ b_ho,
                            const u64* __restrict__ hpack,
                            float* __restrict__ out)
{
    const u64* hf  = hpack + 1 * HID;            // dir0 buf1
    const u64* hbk = hpack + 2 * HID + 1 * HID;  // dir1 buf1
    __shared__ float r0[4], r1[4], r2[4];
    int tid = threadIdx.x;  // 256
    float p0 = 0.f, p1 = 0.f, p2 = 0.f;
    for (int i = tid; i < 2 * HID; i += 256) {
        u64 e = (i < HID) ? hf[i] : hbk[i - HID];
        float hv = __uint_as_float((unsigned)(e & 0xffffffffu));
        p0 += W_ho[0 * 2 * HID + i] * hv;
        p1 += W_ho[1 * 2 * HID + i] * hv;
        p2 += W_ho[2 * 2 * HID + i] * hv;
    }
    #pragma unroll
    for (int m = 1; m < 64; m <<= 1) {
        p0 += __shfl_xor(p0, m);
        p1 += __shfl_xor(p1, m);
        p2 += __shfl_xor(p2, m);
    }
    int w = tid >> 6;
    if ((tid & 63) == 0) { r0[w] = p0; r1[w] = p1; r2[w] = p2; }
    __syncthreads();
    if (tid == 0) {
        out[0] = b_ho[0] + r0[0] + r0[1] + r0[2] + r0[3];
        out[1] = b_ho[1] + r1[0] + r1[1] + r1[2] + r1[3];
        out[2] = b_ho[2] + r2[0] + r2[1] + r2[2] + r2[3];
    }
}

extern "C" void kernel_launch(void* const* d_in, const int* in_sizes, int n_in,
                              void* d_out, int out_size, void* d_ws, size_t ws_size,
                              hipStream_t stream) {
    const float* x     = (const float*)d_in[0];
    const float* Wih_f = (const float*)d_in[1];
    const float* Whh_f = (const float*)d_in[2];
    const float* bih_f = (const float*)d_in[3];
    const float* bhh_f = (const float*)d_in[4];
    const float* Wih_b = (const float*)d_in[5];
    const float* Whh_b = (const float*)d_in[6];
    const float* bih_b = (const float*)d_in[7];
    const float* bhh_b = (const float*)d_in[8];
    const float* W_ho  = (const float*)d_in[9];
    const float* b_ho  = (const float*)d_in[10];

    u64* hpack = (u64*)d_ws;                       // 32 KB packed (tag|h)
    float* xg = (float*)((char*)d_ws + 32768);     // 128 MB xg buffer

    // zero tags every call (ws poisoned once, never re-poisoned between replays)
    hipMemsetAsync(d_ws, 0, 2 * 2 * HID * sizeof(u64), stream);

    dim3 gg(4096 / GN, T_SEQ / GM, 2);
    xproj_gemm<<<gg, 256, 0, stream>>>(x, Wih_f, bih_f, bhh_f,
                                       Wih_b, bih_b, bhh_b, xg);
    bilstm_rec<<<NB_TOT, NTHR, 0, stream>>>(xg, Whh_f, Whh_b, hpack);
    head_kernel<<<1, 256, 0, stream>>>(W_ho, b_ho, hpack, (float*)d_out);
}